// Round 3
// baseline (184.773 us; speedup 1.0000x reference)
//
#include <hip/hip_runtime.h>

typedef _Float16 half8 __attribute__((ext_vector_type(8)));
typedef float floatx4 __attribute__((ext_vector_type(4)));

#define BB 8
#define CC 64
#define HH 128
#define WW 256
#define DD 64
#define OPITCH 36     // Ob row pitch (floats): bank=(4d+w)&31 -> <=2 lanes/bank

// out[b,d,h,w] = (1/64) sum_c L[b,c,h,w] * R[b,c,h,w-d], 0 where w<d.
// Banded Gram via mfma_f32_16x16x32_f16.
// R7: coalesced LDS-transposed epilogue (WRITE_SIZE now exactly out-size;
//     RFO gone). 63.5us but VALUBusy 4.6% / HBM 26% -> still latency-bound.
// R8: kill the barrier phase-lock. 512-thread blocks drained vmcnt(0) at 4
//     barriers/row across 8 waves; loads were in flight only in a narrow
//     window (R6: adding a 2nd phase-locked block/CU was null). Now one
//     64-thread wave = one independent task (32-w tile of one (b,h) row):
//     private 16KB LDS (L 32x64, R band 96x64 f16, same verified swizzle,
//     indices rebased local), zero inter-wave barriers (1-wave WG ->
//     s_barrier elides to waitcnt). ~10 independent waves/CU each with up
//     to 24 dwordx4 in flight -> ~10x per-CU outstanding bytes. Staged
//     loads (L+Rblk2 -> cvt L -> Rblk1 -> ...) bound VGPR for 3 waves/EU.
//     XCD-affine swizzle: the 8 tiles of a row run adjacently on one XCD
//     so the 3x R-band overlap re-reads hit that XCD's L2, not HBM.
__global__ __launch_bounds__(64, 3)
void corr_volume_mfma(const float* __restrict__ left,
                      const float* __restrict__ right,
                      float* __restrict__ out) {
    __shared__ alignas(16) unsigned char smem[16384];
    _Float16* const Lb = (_Float16*)smem;            // [32][64]  4 KiB
    _Float16* const Rb = (_Float16*)(smem + 4096);   // [96][64] 12 KiB
    float*    const Ob = (float*)smem;               // [64][36] overlay 9216 B

    const int lane = threadIdx.x;                    // 0..63

    // XCD-affine bijective swizzle: 8192 blocks, XCD = bid%8 (round-robin);
    // task id tsk = (bid%8)*1024 + bid/8 gives each XCD 128 whole rows with
    // a row's 8 tiles on consecutive per-XCD slots (L2 reuse of R overlap).
    const int tsk = (blockIdx.x & 7) * 1024 + (blockIdx.x >> 3);
    const int bh  = tsk >> 3;
    const int W0  = (tsk & 7) * 32;    // tile base w
    const int b   = bh >> 7;
    const int h   = bh & 127;

    const size_t chanStride = (size_t)HH * WW;       // 32768
    const size_t rowBase = (size_t)b * CC * chanStride + (size_t)h * WW;

    const int cg = lane >> 3;          // this lane's channel group (8 ch)
    const int wq = (lane & 7) * 4;     // this lane's w-quad within the tile

    const float* lp = left  + rowBase + (size_t)(cg * 8) * chanStride;
    const float* rp = right + rowBase + (size_t)(cg * 8) * chanStride;

    float4 lv[8], ra[8], rbv[8];

    // ---- issue L tile + R block2 (always valid: w' = W0+wq >= 0) ----
    #pragma unroll
    for (int c = 0; c < 8; ++c)
        lv[c] = *(const float4*)(lp + (size_t)c * chanStride + (W0 + wq));
    #pragma unroll
    for (int c = 0; c < 8; ++c)
        ra[c] = *(const float4*)(rp + (size_t)c * chanStride + (W0 + wq));

    // zero-fill pad rows j < 64-W0 (only tiles 0,1 have w'<0 in band)
    if (W0 < 64) {
        const int nz8 = (64 - W0) * 8;               // half8 slots to zero
        half8 z = {0, 0, 0, 0, 0, 0, 0, 0};
        for (int zz = lane; zz < nz8; zz += 64)
            *(half8*)&Rb[zz * 8] = z;
    }

    // ---- cvt + stage L (reg-dep waits only on lv; ra still in flight) ----
    {
        const float* lf = (const float*)lv;
        #pragma unroll
        for (int s = 0; s < 4; ++s) {
            const int j   = wq + s;
            const int col = (cg ^ (j & 7)) * 8;
            half8 v;
            #pragma unroll
            for (int c = 0; c < 8; ++c) v[c] = (_Float16)lf[c * 4 + s];
            *(half8*)&Lb[j * 64 + col] = v;
        }
    }

    // ---- issue R block1 (w' = W0-32+wq), valid for W0>=32 ----
    if (W0 >= 32) {
        #pragma unroll
        for (int c = 0; c < 8; ++c)
            rbv[c] = *(const float4*)(rp + (size_t)c * chanStride + (W0 - 32 + wq));
    }

    // ---- stage R block2 -> rows 64..95 ----
    {
        const float* rf = (const float*)ra;
        #pragma unroll
        for (int s = 0; s < 4; ++s) {
            const int j   = 64 + wq + s;
            const int col = (cg ^ (j & 7)) * 8;
            half8 v;
            #pragma unroll
            for (int c = 0; c < 8; ++c) v[c] = (_Float16)rf[c * 4 + s];
            *(half8*)&Rb[j * 64 + col] = v;
        }
    }

    // ---- issue R block0 (w' = W0-64+wq), valid for W0>=64 (reuse ra) ----
    if (W0 >= 64) {
        #pragma unroll
        for (int c = 0; c < 8; ++c)
            ra[c] = *(const float4*)(rp + (size_t)c * chanStride + (W0 - 64 + wq));
    }

    // ---- stage R block1 -> rows 32..63 ----
    if (W0 >= 32) {
        const float* rf = (const float*)rbv;
        #pragma unroll
        for (int s = 0; s < 4; ++s) {
            const int j   = 32 + wq + s;
            const int col = (cg ^ (j & 7)) * 8;
            half8 v;
            #pragma unroll
            for (int c = 0; c < 8; ++c) v[c] = (_Float16)rf[c * 4 + s];
            *(half8*)&Rb[j * 64 + col] = v;
        }
    }

    // ---- stage R block0 -> rows 0..31 ----
    if (W0 >= 64) {
        const float* rf = (const float*)ra;
        #pragma unroll
        for (int s = 0; s < 4; ++s) {
            const int j   = wq + s;
            const int col = (cg ^ (j & 7)) * 8;
            half8 v;
            #pragma unroll
            for (int c = 0; c < 8; ++c) v[c] = (_Float16)rf[c * 4 + s];
            *(half8*)&Rb[j * 64 + col] = v;
        }
    }

    __syncthreads();   // 1-wave WG: pure waitcnt, no cross-wave stall

    // ---------------- MFMA (identical band algebra, local indices) -------
    const int n = lane & 15;           // MFMA col (w) / A row
    const int q = lane >> 4;           // quad
    const float scale = 1.0f / 64.0f;

    floatx4 acc[2][5];
    #pragma unroll
    for (int tt = 0; tt < 2; ++tt)
        #pragma unroll
        for (int u = 0; u < 5; ++u)
            #pragma unroll
            for (int r = 0; r < 4; ++r)
                acc[tt][u][r] = 0.0f;

    #pragma unroll
    for (int kk = 0; kk < 2; ++kk) {
        const int col = ((kk * 4 + q) ^ (n & 7)) * 8;
        half8 bfrag[2], afrag[6];
        #pragma unroll
        for (int tt = 0; tt < 2; ++tt)
            bfrag[tt] = *(const half8*)&Lb[(tt * 16 + n) * 64 + col];
        #pragma unroll
        for (int a = 0; a < 6; ++a)
            afrag[a] = *(const half8*)&Rb[(a * 16 + n) * 64 + col];
        #pragma unroll
        for (int tt = 0; tt < 2; ++tt)
            #pragma unroll
            for (int u = 0; u < 5; ++u)
                acc[tt][u] = __builtin_amdgcn_mfma_f32_16x16x32_f16(
                    afrag[tt + u], bfrag[tt], acc[tt][u], 0, 0, 0);
    }

    __syncthreads();   // fragment reads done; Lb/Rb dead -> Ob overlay

    // acc -> Ob[d][wloc]. C/D: col = n (w), row m = q*4+r. d = 64-16u+n-m.
    #pragma unroll
    for (int tt = 0; tt < 2; ++tt) {
        const int wloc = tt * 16 + n;
        #pragma unroll
        for (int u = 0; u < 5; ++u) {
            #pragma unroll
            for (int r = 0; r < 4; ++r) {
                const int d = 64 - 16 * u + n - (q * 4 + r);
                if (d >= 0 && d < DD) {
                    Ob[d * OPITCH + wloc] = acc[tt][u][r] * scale;
                }
            }
        }
    }

    __syncthreads();   // Ob complete

    // Coalesced full-line stores: 8 instrs, each writes 8 d-rows x 128 B.
    #pragma unroll
    for (int ii = 0; ii < 8; ++ii) {
        const int d    = ii * 8 + (lane >> 3);
        const int wloc = (lane & 7) * 4;
        const float4 v = *(const float4*)&Ob[d * OPITCH + wloc];
        *(float4*)&out[(((size_t)b * DD + d) * HH + h) * WW + W0 + wloc] = v;
    }
}

extern "C" void kernel_launch(void* const* d_in, const int* in_sizes, int n_in,
                              void* d_out, int out_size, void* d_ws, size_t ws_size,
                              hipStream_t stream) {
    const float* left  = (const float*)d_in[0];
    const float* right = (const float*)d_in[1];
    float* out = (float*)d_out;

    dim3 grid(8192);    // 1024 rows x 8 w-tiles; one 64-thread wave per task
    dim3 block(64);
    corr_volume_mfma<<<grid, block, 0, stream>>>(left, right, out);
}